// Round 4
// baseline (415.956 us; speedup 1.0000x reference)
//
#include <hip/hip_runtime.h>
#include <math.h>

#define EPS 1e-5f

typedef short short8 __attribute__((ext_vector_type(8)));
typedef __bf16 bf16x8 __attribute__((ext_vector_type(8)));
typedef float f32x4  __attribute__((ext_vector_type(4)));

__device__ __forceinline__ float lrelu(float x){ return x >= 0.f ? x : 0.2f*x; }

// round-to-nearest-even f32 -> bf16 bits
__device__ __forceinline__ short f2bf_s(float x){
    unsigned u = __float_as_uint(x);
    unsigned r = (u + 0x7FFFu + ((u >> 16) & 1u)) >> 16;
    return (short)r;
}
__device__ __forceinline__ float bfs2f(short h){
    return __uint_as_float(((unsigned)(unsigned short)h) << 16);
}

__device__ __forceinline__ f32x4 mfma16(bf16x8 a, bf16x8 b, f32x4 c){
    return __builtin_amdgcn_mfma_f32_16x16x32_bf16(a, b, c, 0, 0, 0);
}

// -----------------------------------------------------------------------------
// 3x3 conv unit (256 outputs), Cin=Cout=3, optional fused input instance-norm.
template<int STRIDE, bool REFLECT, bool NORM>
__device__ __forceinline__ void conv3_unit(
    int u, const float* __restrict__ in_, int H, int Wd,
    const float* __restrict__ wgt, const float* __restrict__ bias,
    const float* __restrict__ nsum, float cntInv,
    float* __restrict__ out, float* __restrict__ sums, float* red)
{
    int oH = (H-1)/STRIDE + 1, oW = (Wd-1)/STRIDE + 1;
    int tid = threadIdx.x;
    size_t idx = (size_t)u*256 + tid;
    int ow = (int)(idx % oW); size_t t = idx / oW;
    int oh = (int)(t % oH); t /= oH;
    int co = (int)(t % 3); int n = (int)(t/3);
    float w[27];
    #pragma unroll
    for (int i=0;i<27;i++) w[i] = wgt[co*27 + i];
    float acc = bias[co];
    #pragma unroll
    for (int ci=0;ci<3;ci++){
        float mm = 0.f, iv = 0.f;
        if (NORM){
            int pr = n*3+ci;
            float m_ = nsum[pr*2]*cntInv;
            float v_ = nsum[pr*2+1]*cntInv - m_*m_;
            mm = m_; iv = rsqrtf(v_ + EPS);
        }
        size_t base = ((size_t)(n*3+ci))*H*Wd;
        #pragma unroll
        for (int kh=0;kh<3;kh++){
            int ih = oh*STRIDE + kh - 1;
            if (REFLECT) ih = ih<0 ? -ih : (ih>=H ? 2*H-2-ih : ih);
            #pragma unroll
            for (int kw=0;kw<3;kw++){
                int iw = ow*STRIDE + kw - 1;
                if (REFLECT) iw = iw<0 ? -iw : (iw>=Wd ? 2*Wd-2-iw : iw);
                bool ok = REFLECT || (ih>=0 && ih<H && iw>=0 && iw<Wd);
                if (ok){
                    float val = in_[base + (size_t)ih*Wd + iw];
                    if (NORM) val = lrelu((val-mm)*iv);
                    acc += w[(ci*3+kh)*3+kw] * val;
                }
            }
        }
    }
    out[idx] = acc;
    red[tid] = acc; __syncthreads();
    for (int o=128;o>0;o>>=1){ if(tid<o) red[tid]+=red[tid+o]; __syncthreads(); }
    float blockSum = red[0]; __syncthreads();
    red[tid] = acc*acc; __syncthreads();
    for (int o=128;o>0;o>>=1){ if(tid<o) red[tid]+=red[tid+o]; __syncthreads(); }
    if (tid==0){
        int pair = n*3+co;
        atomicAdd(&sums[pair*2],   blockSum);
        atomicAdd(&sums[pair*2+1], red[0]);
    }
    __syncthreads();
}

// -----------------------------------------------------------------------------
// mega1: independent-work merge, NO grid barrier.
//   blocks 0-255 : feat conv1x1 (256->64) + bias -> FEAT raw, FSUM atomics
//   blocks 256-639: fc conv#1 (256->128, reflect, s2) -> CONV1, SUMS+0
__global__ __launch_bounds__(256,2) void mega1(
    const float* __restrict__ fa_raw, const float* __restrict__ fb_raw,
    const float* __restrict__ Wa, const float* __restrict__ Wb,
    const float* __restrict__ ba, const float* __restrict__ bb,
    float* __restrict__ Y, float* __restrict__ FSUM,
    const float* __restrict__ fc_raw,
    const float* __restrict__ Wc1, const float* __restrict__ bc1,
    float* __restrict__ CONV1, float* __restrict__ SUMS)
{
    __shared__ float sh[17664];   // feat: wS[256*65] | xS[16*64]; conv: red[256]
    int blk = blockIdx.x, tid = threadIdx.x;

    if (blk < 256){
        int pch = blk & 63, n = (blk>>6)&1, side = blk>>7;
        int p0 = pch*64;
        const float* x    = (side ? fb_raw : fa_raw) + (size_t)n*256*4096 + p0;
        const float* W    = side ? Wb : Wa;
        const float* bias = side ? bb : ba;
        float* wS = sh;            // [ci][co], pad 65
        float* xS = sh + 16640;    // [ci_l][p]

        #pragma unroll
        for (int it=0; it<64; it++){
            int idx = it*256 + tid;
            int co = idx >> 8, ci = idx & 255;
            wS[ci*65 + co] = W[idx];
        }

        int pl = tid & 63, cog = tid >> 6;
        float acc[16];
        #pragma unroll
        for (int j=0;j<16;j++) acc[j] = 0.f;

        for (int cb=0; cb<16; cb++){
            __syncthreads();
            #pragma unroll
            for (int it=0; it<4; it++){
                int idx = it*256 + tid;
                int cl = idx >> 6, pp = idx & 63;
                xS[idx] = x[(size_t)(cb*16+cl)*4096 + pp];
            }
            __syncthreads();
            #pragma unroll
            for (int cl=0; cl<16; cl++){
                float xr = xS[cl*64 + pl];
                const float* wr = &wS[(cb*16+cl)*65 + cog*16];
                #pragma unroll
                for (int j=0;j<16;j++) acc[j] = fmaf(xr, wr[j], acc[j]);
            }
        }

        int pair = side*2 + n;
        #pragma unroll
        for (int j=0;j<16;j++){
            acc[j] += bias[cog*16+j];
            float v = acc[j], v2 = v*v;
            #pragma unroll
            for (int off=1; off<64; off<<=1){
                v  += __shfl_xor(v,  off);
                v2 += __shfl_xor(v2, off);
            }
            if (pl == 0){
                atomicAdd(&FSUM[(pair*64 + cog*16 + j)*2],   v);
                atomicAdd(&FSUM[(pair*64 + cog*16 + j)*2+1], v2);
            }
        }

        float* yr = Y + ((size_t)pair*4096 + p0 + pl)*64 + cog*16;
        #pragma unroll
        for (int j4=0;j4<4;j4++)
            *(float4*)(yr + j4*4) = make_float4(acc[j4*4],acc[j4*4+1],acc[j4*4+2],acc[j4*4+3]);
    } else {
        conv3_unit<2,true,false>(blk-256, fc_raw, 256,256, Wc1, bc1, nullptr, 0.f,
                                 CONV1, SUMS, sh);
    }
}

// -----------------------------------------------------------------------------
// mega2: independent-work merge, NO grid barrier.
//   blocks 0-255 : feat IN+lrelu sum pass (read-only, accumulates M2SUM)
//   blocks 256-351: fc conv#2 (128->64, reflect, s2) with fused input-norm
//   block  352   : FST precompute (per-channel mean / rstd from FSUM)
__global__ __launch_bounds__(256) void mega2(
    const float* __restrict__ Y, const float* __restrict__ FSUM,
    float* __restrict__ M2SUM,
    const float* __restrict__ CONV1,
    const float* __restrict__ Wc2, const float* __restrict__ bc2,
    float* __restrict__ SUMS, float* __restrict__ FC64,
    float* __restrict__ FSTm, float* __restrict__ FSTi)
{
    __shared__ float red[256];
    int blk = blockIdx.x, tid = threadIdx.x;

    if (blk < 256){
        size_t base = (size_t)blk*4096;
        int pair = blk >> 6;
        int co = tid & 63;
        int ch = pair*64 + co;
        float m   = FSUM[ch*2]   * (1.f/4096.f);
        float var = FSUM[ch*2+1] * (1.f/4096.f) - m*m;
        float inv = rsqrtf(var + EPS);
        float asum = 0.f;
        #pragma unroll
        for (int it=0; it<16; it++){
            size_t idx = base + it*256 + tid;
            asum += lrelu((Y[idx]-m)*inv);
        }
        red[tid] = asum; __syncthreads();
        if (tid < 64)
            atomicAdd(&M2SUM[pair*64 + tid], red[tid]+red[tid+64]+red[tid+128]+red[tid+192]);
    } else if (blk < 352){
        conv3_unit<2,true,true>(blk-256, CONV1, 128,128, Wc2, bc2, SUMS+0, 1.f/16384.f,
                                FC64, SUMS+12, red);
    } else {
        int ch = tid;   // 256 channels
        float m   = FSUM[ch*2]   * (1.f/4096.f);
        float var = FSUM[ch*2+1] * (1.f/4096.f) - m*m;
        FSTm[ch] = m;
        FSTi[ch] = rsqrtf(var + EPS);
    }
}

// -----------------------------------------------------------------------------
// feat_finish: recompute IN+lrelu (bitwise-identical to mega2's values),
// re-center by M2SUM mean, L2-normalize over channels, pack PK (bf16 hi|lo).
__global__ void feat_finish(const float* __restrict__ Y, const float* __restrict__ M2SUM,
                            const float* __restrict__ FSTm, const float* __restrict__ FSTi,
                            short* __restrict__ PK)
{
    int r = blockIdx.x*256 + threadIdx.x;
    int pair = r >> 12;
    int p = r & 4095;
    const float4* m4  = (const float4*)(M2SUM + pair*64);
    const float4* cm4 = (const float4*)(FSTm + pair*64);
    const float4* ci4 = (const float4*)(FSTi + pair*64);
    const float4* r4  = (const float4*)(Y + (size_t)r*64);
    float s = 0.f;
    float4 v[16];
    #pragma unroll
    for (int i=0;i<16;i++){
        float4 t = r4[i], mm = m4[i], cm = cm4[i], ci = ci4[i];
        t.x = lrelu((t.x-cm.x)*ci.x) - mm.x*(1.f/4096.f);
        t.y = lrelu((t.y-cm.y)*ci.y) - mm.y*(1.f/4096.f);
        t.z = lrelu((t.z-cm.z)*ci.z) - mm.z*(1.f/4096.f);
        t.w = lrelu((t.w-cm.w)*ci.w) - mm.w*(1.f/4096.f);
        v[i] = t;
        s += t.x*t.x + t.y*t.y + t.z*t.z + t.w*t.w;
    }
    float inv = 1.f/(sqrtf(s)+EPS);
    #pragma unroll
    for (int i=0;i<16;i++){ v[i].x*=inv; v[i].y*=inv; v[i].z*=inv; v[i].w*=inv; }

    int qb = p >> 7, rr = p & 127, g = rr >> 4, rl = rr & 15;
    short* blk = PK + (((size_t)pair*32 + qb) << 14);   // *16384 shorts
    #pragma unroll
    for (int c=0;c<8;c++){
        float x[8] = {v[2*c].x, v[2*c].y, v[2*c].z, v[2*c].w,
                      v[2*c+1].x, v[2*c+1].y, v[2*c+1].z, v[2*c+1].w};
        short8 h, l;
        #pragma unroll
        for (int j=0;j<8;j++){
            short hh = f2bf_s(x[j]);
            h[j] = hh;
            l[j] = f2bf_s(x[j] - bfs2f(hh));
        }
        int idx = g*128 + c*16 + rl;
        *(short8*)(blk + idx*8)        = h;
        *(short8*)(blk + 8192 + idx*8) = l;
    }
}

// -----------------------------------------------------------------------------
// LDS-staged fused bilinear-up2x + zero-pad 3x3 conv, Cin=Cout=3.
// Block = ROWS output rows of one (n,co) plane. Stage (ROWS+2) up-rows x
// (oH+2) cols x 3 ci of bilinear-upsampled (optionally instance-normed)
// values into LDS cooperatively (coalesced), then conv = 27 stride-1 LDS
// reads per thread. Replaces the latency-bound 108-scattered-load version.
template<int H, int ROWS, bool NORM>
__global__ __launch_bounds__(256) void upconv2_kernel(
    const float* __restrict__ in_, const float* __restrict__ wgt,
    const float* __restrict__ bias, const float* __restrict__ nsum, float cntInv,
    float* __restrict__ out, float* __restrict__ sums)
{
    const int oH = 2*H;
    const int N_UH = ROWS+2, N_UW = oH+2;
    __shared__ float upS[3][N_UH][N_UW];
    __shared__ float red[256];

    const int nRowGrp = oH / ROWS;
    int blk = blockIdx.x, tid = threadIdx.x;
    int plane = blk / nRowGrp, ohg = blk % nRowGrp;
    int n = plane / 3, co = plane % 3;
    int oh0 = ohg * ROWS;

    // stage: bilinear up-values (optionally normed) into LDS
    for (int it = tid; it < 3*N_UH*N_UW; it += 256){
        int ci  = it / (N_UH*N_UW);
        int rem = it - ci*(N_UH*N_UW);
        int ur  = rem / N_UW;
        int uwi = rem - ur*N_UW;
        int uh = oh0 - 1 + ur;
        int uw = uwi - 1;
        float val = 0.f;
        if (uh >= 0 && uh < oH && uw >= 0 && uw < oH){
            float ph = (float)uh * (float)(H-1) / (float)(oH-1);
            int i0 = (int)ph; int i1 = min(i0+1, H-1); float fh = ph - (float)i0;
            float pw = (float)uw * (float)(H-1) / (float)(oH-1);
            int j0 = (int)pw; int j1 = min(j0+1, H-1); float fw = pw - (float)j0;
            const float* p = in_ + ((size_t)(n*3+ci))*H*H;
            float v00 = p[(size_t)i0*H + j0], v01 = p[(size_t)i0*H + j1];
            float v10 = p[(size_t)i1*H + j0], v11 = p[(size_t)i1*H + j1];
            if (NORM){
                int pr = n*3+ci;
                float m_ = nsum[pr*2]*cntInv;
                float v_ = nsum[pr*2+1]*cntInv - m_*m_;
                float iv = rsqrtf(v_ + EPS);
                v00 = lrelu((v00-m_)*iv); v01 = lrelu((v01-m_)*iv);
                v10 = lrelu((v10-m_)*iv); v11 = lrelu((v11-m_)*iv);
            }
            float v0 = v00 + (v01-v00)*fw;
            float v1 = v10 + (v11-v10)*fw;
            val = v0 + (v1-v0)*fh;
        }
        upS[ci][ur][uwi] = val;
    }
    __syncthreads();

    int lrow = tid / oH;            // compile-time shift
    int ow   = tid - lrow*oH;
    int oh   = oh0 + lrow;

    float w[27];
    #pragma unroll
    for (int i=0;i<27;i++) w[i] = wgt[co*27 + i];

    float acc = bias[co];
    #pragma unroll
    for (int ci=0;ci<3;ci++)
        #pragma unroll
        for (int kh=0;kh<3;kh++)
            #pragma unroll
            for (int kw=0;kw<3;kw++)
                acc += w[(ci*3+kh)*3+kw] * upS[ci][lrow+kh][ow+kw];

    size_t idx = (((size_t)(n*3+co))*oH + oh)*oH + ow;
    out[idx] = acc;

    red[tid] = acc; __syncthreads();
    for (int o=128;o>0;o>>=1){ if(tid<o) red[tid]+=red[tid+o]; __syncthreads(); }
    float blockSum = red[0]; __syncthreads();
    red[tid] = acc*acc; __syncthreads();
    for (int o=128;o>0;o>>=1){ if(tid<o) red[tid]+=red[tid+o]; __syncthreads(); }
    if (tid==0){
        int pair = n*3+co;
        atomicAdd(&sums[pair*2],   blockSum);
        atomicAdd(&sums[pair*2+1], red[0]);
    }
}

__global__ void inapply_kernel(const float* __restrict__ in, const float* __restrict__ sums,
                               int planeSize, float cntInv, float* __restrict__ out)
{
    size_t idx = (size_t)blockIdx.x*256 + threadIdx.x;
    int pair = (int)(idx / planeSize);
    float m = sums[pair*2]*cntInv;
    float v = sums[pair*2+1]*cntInv - m*m;
    float inv = rsqrtf(v + EPS);
    out[idx] = lrelu((in[idx]-m)*inv);
}

// -----------------------------------------------------------------------------
// MFMA correlation, 3-term bf16 split, two-pass recompute. PASS1 applies the
// fc instance-norm inline (reads raw FC64 + SUMS+12).
template<int PASS>
__global__ __launch_bounds__(256,2) void corr_mfma(
    const short* __restrict__ PK,
    float* __restrict__ corr, float* __restrict__ SSUM,
    const float* __restrict__ FC64, const float* __restrict__ fsums,
    float* __restrict__ WARP)
{
    __shared__ short lds[32768];   // 64KB: fb_hi|fb_lo|fa_hi|fa_lo, 8192 each

    int blk = blockIdx.x;
    int qb = blk & 31, pb = (blk >> 5) & 31, n = blk >> 10;
    int tid = threadIdx.x;

    const short* pkB = PK + (((size_t)(2+n)*32 + pb) << 14);
    const short* pkA = PK + (((size_t)( n )*32 + qb) << 14);
    #pragma unroll
    for (int it=0; it<16; it++){
        int cid = it*256 + tid;
        int side = cid >> 11;
        int off  = (cid & 2047)*8;
        short8 vv = *(const short8*)((side ? pkA : pkB) + off);
        *(short8*)(lds + side*16384 + off) = vv;
    }
    __syncthreads();

    int wave = tid >> 6, lane = tid & 63;
    int wp = wave >> 1, wq = wave & 1;
    int quad = lane >> 4, l16 = lane & 15;

    f32x4 acc[4][4];
    #pragma unroll
    for (int pt=0;pt<4;pt++)
        #pragma unroll
        for (int qt=0;qt<4;qt++)
            acc[pt][qt] = (f32x4){0.f,0.f,0.f,0.f};

    #pragma unroll
    for (int kc=0;kc<2;kc++){
        int cc = kc*4 + quad;
        bf16x8 Ah[4], Al[4], Bh[4], Bl[4];
        #pragma unroll
        for (int t4=0;t4<4;t4++){
            int offA = (((wp*4+t4)*8 + cc)*16 + l16)*8;
            Ah[t4] = (bf16x8)(*(const short8*)(lds + offA));
            Al[t4] = (bf16x8)(*(const short8*)(lds + 8192 + offA));
            int offB = 16384 + (((wq*4+t4)*8 + cc)*16 + l16)*8;
            Bh[t4] = (bf16x8)(*(const short8*)(lds + offB));
            Bl[t4] = (bf16x8)(*(const short8*)(lds + 8192 + offB));
        }
        #pragma unroll
        for (int pt=0;pt<4;pt++)
            #pragma unroll
            for (int qt=0;qt<4;qt++){
                acc[pt][qt] = mfma16(Ah[pt], Bh[qt], acc[pt][qt]);
                acc[pt][qt] = mfma16(Ah[pt], Bl[qt], acc[pt][qt]);
                acc[pt][qt] = mfma16(Al[pt], Bh[qt], acc[pt][qt]);
            }
    }

    if (PASS == 0){
        float colsum[4] = {0.f,0.f,0.f,0.f};
        #pragma unroll
        for (int pt=0;pt<4;pt++)
            #pragma unroll
            for (int qt=0;qt<4;qt++)
                #pragma unroll
                for (int i=0;i<4;i++)
                    colsum[qt] += __expf(fmaf(acc[pt][qt][i], 100.f, -64.f));
        #pragma unroll
        for (int qt=0;qt<4;qt++){
            float v = colsum[qt];
            v += __shfl_xor(v, 16);
            v += __shfl_xor(v, 32);
            if (lane < 16)
                atomicAdd(&SSUM[n*4096 + qb*128 + wq*64 + qt*16 + lane], v);
        }
    } else {
        float inv4[4];
        int qoff = n*4096 + qb*128 + wq*64 + l16;
        #pragma unroll
        for (int qt=0;qt<4;qt++) inv4[qt] = 1.f / SSUM[qoff + qt*16];

        // fc instance-norm params (fused inapply)
        float fm[3], fiv[3];
        #pragma unroll
        for (int c=0;c<3;c++){
            float m_ = fsums[(n*3+c)*2]   * (1.f/4096.f);
            float v_ = fsums[(n*3+c)*2+1] * (1.f/4096.f) - m_*m_;
            fm[c] = m_; fiv[c] = rsqrtf(v_ + EPS);
        }

        float wa0[4]={0,0,0,0}, wa1[4]={0,0,0,0}, wa2[4]={0,0,0,0};
        const float* fcb = FC64 + (size_t)n*12288;
        float* corrN = corr + (size_t)n*4096*4096;
        #pragma unroll
        for (int pt=0;pt<4;pt++){
            #pragma unroll
            for (int i=0;i<4;i++){
                int p = pb*128 + wp*64 + pt*16 + quad*4 + i;
                float f0 = lrelu((fcb[p]      -fm[0])*fiv[0]);
                float f1 = lrelu((fcb[4096+p] -fm[1])*fiv[1]);
                float f2 = lrelu((fcb[8192+p] -fm[2])*fiv[2]);
                float* rowp = corrN + (size_t)p*4096 + qb*128 + wq*64 + l16;
                #pragma unroll
                for (int qt=0;qt<4;qt++){
                    float u = __expf(fmaf(acc[pt][qt][i], 100.f, -64.f)) * inv4[qt];
                    __builtin_nontemporal_store(u, &rowp[qt*16]);
                    wa0[qt] += f0*u; wa1[qt] += f1*u; wa2[qt] += f2*u;
                }
            }
        }
        #pragma unroll
        for (int qt=0;qt<4;qt++){
            float v0 = wa0[qt], v1 = wa1[qt], v2 = wa2[qt];
            v0 += __shfl_xor(v0,16); v0 += __shfl_xor(v0,32);
            v1 += __shfl_xor(v1,16); v1 += __shfl_xor(v1,32);
            v2 += __shfl_xor(v2,16); v2 += __shfl_xor(v2,32);
            if (lane < 16){
                int q = qb*128 + wq*64 + qt*16 + lane;
                atomicAdd(&WARP[(size_t)n*12288 +        q], v0);
                atomicAdd(&WARP[(size_t)n*12288 + 4096 + q], v1);
                atomicAdd(&WARP[(size_t)n*12288 + 8192 + q], v2);
            }
        }
    }
}

// -----------------------------------------------------------------------------
extern "C" void kernel_launch(void* const* d_in, const int* in_sizes, int n_in,
                              void* d_out, int out_size, void* d_ws, size_t ws_size,
                              hipStream_t stream)
{
    const float* fa_raw = (const float*)d_in[0];
    const float* fb_raw = (const float*)d_in[1];
    const float* fc_raw = (const float*)d_in[2];
    const float* Wa  = (const float*)d_in[3];
    const float* ba  = (const float*)d_in[4];
    const float* Wb  = (const float*)d_in[5];
    const float* bb  = (const float*)d_in[6];
    const float* Wc1 = (const float*)d_in[7];
    const float* bc1 = (const float*)d_in[8];
    const float* Wc2 = (const float*)d_in[9];
    const float* bc2 = (const float*)d_in[10];
    const float* Wu1 = (const float*)d_in[11];
    const float* bu1 = (const float*)d_in[12];
    const float* Wu2 = (const float*)d_in[13];
    const float* bu2 = (const float*)d_in[14];

    float* ws    = (float*)d_ws;
    float* FEAT  = ws;                  // 1048576 = [side][n][4096][64]
    float* CONV1 = FEAT  + 1048576;     // 98304
    float* FC64  = CONV1 + 98304;       // 24576
    float* CONV2 = FC64  + 24576;       // 98304
    float* CONV3 = CONV2 + 98304;       // 393216
    float* SSUM  = CONV3 + 393216;      // 8192   [zeroed]
    float* SUMS  = SSUM  + 8192;        // 48     [zeroed]
    float* FSUM  = SUMS  + 48;          // 512    [zeroed]
    float* M2SUM = FSUM  + 512;         // 256    [zeroed]
    float* WARP  = M2SUM + 256;         // 24576  [zeroed]
    float* FSTm  = WARP  + 24576;       // 256
    float* FSTi  = FSTm  + 256;         // 256
    short* PK    = (short*)(FSTi + 256); // 2097152 shorts (4 MB), 16B-aligned

    float* out_fc   = (float*)d_out;
    float* out_corr = out_fc + 393216;

    // zero atomic accumulators (SSUM..WARP contiguous, 33584 floats)
    hipMemsetAsync(SSUM, 0, (size_t)(8192 + 48 + 512 + 256 + 24576)*sizeof(float), stream);

    // stage 1: feat conv1x1 || fc conv#1   (independent work, one dispatch)
    mega1<<<640,256,0,stream>>>(fa_raw, fb_raw, Wa, Wb, ba, bb, FEAT, FSUM,
                                fc_raw, Wc1, bc1, CONV1, SUMS+0);

    // stage 2: feat IN-sum || fc conv#2 (norm-fused) || FST precompute
    mega2<<<353,256,0,stream>>>(FEAT, FSUM, M2SUM, CONV1, Wc2, bc2, SUMS, FC64,
                                FSTm, FSTi);

    // stage 3: feat recenter + L2-norm + PK pack
    feat_finish<<<64,256,0,stream>>>(FEAT, M2SUM, FSTm, FSTi, PK);

    // correlation softmax (two-pass MFMA recompute) + fused warp + fused fc-norm
    corr_mfma<0><<<2048,256,0,stream>>>(PK, out_corr, SSUM, FC64, SUMS+12, WARP);
    corr_mfma<1><<<2048,256,0,stream>>>(PK, out_corr, SSUM, FC64, SUMS+12, WARP);

    // upsample block 1: 64 -> 128 (raw WARP input), LDS-staged
    upconv2_kernel<64,2,false><<<384,256,0,stream>>>(WARP, Wu1, bu1, nullptr, 0.f,
                                                     CONV2, SUMS+24);
    // upsample block 2: 128 -> 256, input-norm fused, LDS-staged
    upconv2_kernel<128,1,true><<<1536,256,0,stream>>>(CONV2, Wu2, bu2, SUMS+24, 1.f/16384.f,
                                                      CONV3, SUMS+36);
    // final instance-norm apply -> out_fc
    inapply_kernel<<<1536,256,0,stream>>>(CONV3, SUMS+36, 65536, 1.f/65536.f, out_fc);
}

// Round 5
// 324.943 us; speedup vs baseline: 1.2801x; 1.2801x over previous
//
#include <hip/hip_runtime.h>
#include <math.h>

#define EPS 1e-5f

typedef short short8 __attribute__((ext_vector_type(8)));
typedef __bf16 bf16x8 __attribute__((ext_vector_type(8)));
typedef float f32x4  __attribute__((ext_vector_type(4)));

__device__ __forceinline__ float lrelu(float x){ return x >= 0.f ? x : 0.2f*x; }

// round-to-nearest-even f32 -> bf16 bits
__device__ __forceinline__ short f2bf_s(float x){
    unsigned u = __float_as_uint(x);
    unsigned r = (u + 0x7FFFu + ((u >> 16) & 1u)) >> 16;
    return (short)r;
}
__device__ __forceinline__ float bfs2f(short h){
    return __uint_as_float(((unsigned)(unsigned short)h) << 16);
}

__device__ __forceinline__ f32x4 mfma16(bf16x8 a, bf16x8 b, f32x4 c){
    return __builtin_amdgcn_mfma_f32_16x16x32_bf16(a, b, c, 0, 0, 0);
}

// -----------------------------------------------------------------------------
// 3x3 conv unit (256 outputs), Cin=Cout=3, optional fused input instance-norm.
template<int STRIDE, bool REFLECT, bool NORM>
__device__ __forceinline__ void conv3_unit(
    int u, const float* __restrict__ in_, int H, int Wd,
    const float* __restrict__ wgt, const float* __restrict__ bias,
    const float* __restrict__ nsum, float cntInv,
    float* __restrict__ out, float* __restrict__ sums, float* red)
{
    int oH = (H-1)/STRIDE + 1, oW = (Wd-1)/STRIDE + 1;
    int tid = threadIdx.x;
    size_t idx = (size_t)u*256 + tid;
    int ow = (int)(idx % oW); size_t t = idx / oW;
    int oh = (int)(t % oH); t /= oH;
    int co = (int)(t % 3); int n = (int)(t/3);
    float w[27];
    #pragma unroll
    for (int i=0;i<27;i++) w[i] = wgt[co*27 + i];
    float acc = bias[co];
    #pragma unroll
    for (int ci=0;ci<3;ci++){
        float mm = 0.f, iv = 0.f;
        if (NORM){
            int pr = n*3+ci;
            float m_ = nsum[pr*2]*cntInv;
            float v_ = nsum[pr*2+1]*cntInv - m_*m_;
            mm = m_; iv = rsqrtf(v_ + EPS);
        }
        size_t base = ((size_t)(n*3+ci))*H*Wd;
        #pragma unroll
        for (int kh=0;kh<3;kh++){
            int ih = oh*STRIDE + kh - 1;
            if (REFLECT) ih = ih<0 ? -ih : (ih>=H ? 2*H-2-ih : ih);
            #pragma unroll
            for (int kw=0;kw<3;kw++){
                int iw = ow*STRIDE + kw - 1;
                if (REFLECT) iw = iw<0 ? -iw : (iw>=Wd ? 2*Wd-2-iw : iw);
                bool ok = REFLECT || (ih>=0 && ih<H && iw>=0 && iw<Wd);
                if (ok){
                    float val = in_[base + (size_t)ih*Wd + iw];
                    if (NORM) val = lrelu((val-mm)*iv);
                    acc += w[(ci*3+kh)*3+kw] * val;
                }
            }
        }
    }
    out[idx] = acc;
    red[tid] = acc; __syncthreads();
    for (int o=128;o>0;o>>=1){ if(tid<o) red[tid]+=red[tid+o]; __syncthreads(); }
    float blockSum = red[0]; __syncthreads();
    red[tid] = acc*acc; __syncthreads();
    for (int o=128;o>0;o>>=1){ if(tid<o) red[tid]+=red[tid+o]; __syncthreads(); }
    if (tid==0){
        int pair = n*3+co;
        atomicAdd(&sums[pair*2],   blockSum);
        atomicAdd(&sums[pair*2+1], red[0]);
    }
    __syncthreads();
}

// -----------------------------------------------------------------------------
// mega1: independent-work merge, NO grid barrier.
//   blocks 0-255 : feat conv1x1 (256->64) + bias -> FEAT raw, FSUM atomics
//   blocks 256-639: fc conv#1 (256->128, reflect, s2) -> CONV1, SUMS+0
__global__ __launch_bounds__(256,2) void mega1(
    const float* __restrict__ fa_raw, const float* __restrict__ fb_raw,
    const float* __restrict__ Wa, const float* __restrict__ Wb,
    const float* __restrict__ ba, const float* __restrict__ bb,
    float* __restrict__ Y, float* __restrict__ FSUM,
    const float* __restrict__ fc_raw,
    const float* __restrict__ Wc1, const float* __restrict__ bc1,
    float* __restrict__ CONV1, float* __restrict__ SUMS)
{
    __shared__ float sh[17664];   // feat: wS[256*65] | xS[16*64]; conv: red[256]
    int blk = blockIdx.x, tid = threadIdx.x;

    if (blk < 256){
        int pch = blk & 63, n = (blk>>6)&1, side = blk>>7;
        int p0 = pch*64;
        const float* x    = (side ? fb_raw : fa_raw) + (size_t)n*256*4096 + p0;
        const float* W    = side ? Wb : Wa;
        const float* bias = side ? bb : ba;
        float* wS = sh;            // [ci][co], pad 65
        float* xS = sh + 16640;    // [ci_l][p]

        #pragma unroll
        for (int it=0; it<64; it++){
            int idx = it*256 + tid;
            int co = idx >> 8, ci = idx & 255;
            wS[ci*65 + co] = W[idx];
        }

        int pl = tid & 63, cog = tid >> 6;
        float acc[16];
        #pragma unroll
        for (int j=0;j<16;j++) acc[j] = 0.f;

        for (int cb=0; cb<16; cb++){
            __syncthreads();
            #pragma unroll
            for (int it=0; it<4; it++){
                int idx = it*256 + tid;
                int cl = idx >> 6, pp = idx & 63;
                xS[idx] = x[(size_t)(cb*16+cl)*4096 + pp];
            }
            __syncthreads();
            #pragma unroll
            for (int cl=0; cl<16; cl++){
                float xr = xS[cl*64 + pl];
                const float* wr = &wS[(cb*16+cl)*65 + cog*16];
                #pragma unroll
                for (int j=0;j<16;j++) acc[j] = fmaf(xr, wr[j], acc[j]);
            }
        }

        int pair = side*2 + n;
        #pragma unroll
        for (int j=0;j<16;j++){
            acc[j] += bias[cog*16+j];
            float v = acc[j], v2 = v*v;
            #pragma unroll
            for (int off=1; off<64; off<<=1){
                v  += __shfl_xor(v,  off);
                v2 += __shfl_xor(v2, off);
            }
            if (pl == 0){
                atomicAdd(&FSUM[(pair*64 + cog*16 + j)*2],   v);
                atomicAdd(&FSUM[(pair*64 + cog*16 + j)*2+1], v2);
            }
        }

        float* yr = Y + ((size_t)pair*4096 + p0 + pl)*64 + cog*16;
        #pragma unroll
        for (int j4=0;j4<4;j4++)
            *(float4*)(yr + j4*4) = make_float4(acc[j4*4],acc[j4*4+1],acc[j4*4+2],acc[j4*4+3]);
    } else {
        conv3_unit<2,true,false>(blk-256, fc_raw, 256,256, Wc1, bc1, nullptr, 0.f,
                                 CONV1, SUMS, sh);
    }
}

// -----------------------------------------------------------------------------
// mega2: independent-work merge, NO grid barrier.
//   blocks 0-255 : feat IN+lrelu sum pass (read-only, accumulates M2SUM)
//   blocks 256-351: fc conv#2 (128->64, reflect, s2) with fused input-norm
//   block  352   : FST precompute (per-channel mean / rstd from FSUM)
__global__ __launch_bounds__(256) void mega2(
    const float* __restrict__ Y, const float* __restrict__ FSUM,
    float* __restrict__ M2SUM,
    const float* __restrict__ CONV1,
    const float* __restrict__ Wc2, const float* __restrict__ bc2,
    float* __restrict__ SUMS, float* __restrict__ FC64,
    float* __restrict__ FSTm, float* __restrict__ FSTi)
{
    __shared__ float red[256];
    int blk = blockIdx.x, tid = threadIdx.x;

    if (blk < 256){
        size_t base = (size_t)blk*4096;
        int pair = blk >> 6;
        int co = tid & 63;
        int ch = pair*64 + co;
        float m   = FSUM[ch*2]   * (1.f/4096.f);
        float var = FSUM[ch*2+1] * (1.f/4096.f) - m*m;
        float inv = rsqrtf(var + EPS);
        float asum = 0.f;
        #pragma unroll
        for (int it=0; it<16; it++){
            size_t idx = base + it*256 + tid;
            asum += lrelu((Y[idx]-m)*inv);
        }
        red[tid] = asum; __syncthreads();
        if (tid < 64)
            atomicAdd(&M2SUM[pair*64 + tid], red[tid]+red[tid+64]+red[tid+128]+red[tid+192]);
    } else if (blk < 352){
        conv3_unit<2,true,true>(blk-256, CONV1, 128,128, Wc2, bc2, SUMS+0, 1.f/16384.f,
                                FC64, SUMS+12, red);
    } else {
        int ch = tid;   // 256 channels
        float m   = FSUM[ch*2]   * (1.f/4096.f);
        float var = FSUM[ch*2+1] * (1.f/4096.f) - m*m;
        FSTm[ch] = m;
        FSTi[ch] = rsqrtf(var + EPS);
    }
}

// -----------------------------------------------------------------------------
// feat_finish: recompute IN+lrelu (bitwise-identical to mega2's values),
// re-center by M2SUM mean, L2-normalize over channels, pack PK (bf16 hi|lo).
__global__ void feat_finish(const float* __restrict__ Y, const float* __restrict__ M2SUM,
                            const float* __restrict__ FSTm, const float* __restrict__ FSTi,
                            short* __restrict__ PK)
{
    int r = blockIdx.x*256 + threadIdx.x;
    int pair = r >> 12;
    int p = r & 4095;
    const float4* m4  = (const float4*)(M2SUM + pair*64);
    const float4* cm4 = (const float4*)(FSTm + pair*64);
    const float4* ci4 = (const float4*)(FSTi + pair*64);
    const float4* r4  = (const float4*)(Y + (size_t)r*64);
    float s = 0.f;
    float4 v[16];
    #pragma unroll
    for (int i=0;i<16;i++){
        float4 t = r4[i], mm = m4[i], cm = cm4[i], ci = ci4[i];
        t.x = lrelu((t.x-cm.x)*ci.x) - mm.x*(1.f/4096.f);
        t.y = lrelu((t.y-cm.y)*ci.y) - mm.y*(1.f/4096.f);
        t.z = lrelu((t.z-cm.z)*ci.z) - mm.z*(1.f/4096.f);
        t.w = lrelu((t.w-cm.w)*ci.w) - mm.w*(1.f/4096.f);
        v[i] = t;
        s += t.x*t.x + t.y*t.y + t.z*t.z + t.w*t.w;
    }
    float inv = 1.f/(sqrtf(s)+EPS);
    #pragma unroll
    for (int i=0;i<16;i++){ v[i].x*=inv; v[i].y*=inv; v[i].z*=inv; v[i].w*=inv; }

    int qb = p >> 7, rr = p & 127, g = rr >> 4, rl = rr & 15;
    short* blk = PK + (((size_t)pair*32 + qb) << 14);   // *16384 shorts
    #pragma unroll
    for (int c=0;c<8;c++){
        float x[8] = {v[2*c].x, v[2*c].y, v[2*c].z, v[2*c].w,
                      v[2*c+1].x, v[2*c+1].y, v[2*c+1].z, v[2*c+1].w};
        short8 h, l;
        #pragma unroll
        for (int j=0;j<8;j++){
            short hh = f2bf_s(x[j]);
            h[j] = hh;
            l[j] = f2bf_s(x[j] - bfs2f(hh));
        }
        int idx = g*128 + c*16 + rl;
        *(short8*)(blk + idx*8)        = h;
        *(short8*)(blk + 8192 + idx*8) = l;
    }
}

// -----------------------------------------------------------------------------
// upconv via raw-row LDS staging: block = (n, 2 output rows, ALL cols, ALL co).
// 1) stage 4 raw input rows x 3 ci (coalesced, norm+lrelu at load if NORM)
// 2) compute bilinear up-halo (4 up-rows x oW+2) from LDS
// 3) 3x3 conv from LDS halo, 3 co outputs per position
// Global loads per thread: 3 (H=64) / 6 (H=128), fully coalesced.
template<int H, bool NORM>
__global__ __launch_bounds__(256) void upconv_lds(
    const float* __restrict__ in_, const float* __restrict__ wgt,
    const float* __restrict__ bias, const float* __restrict__ nsum, float cntInv,
    float* __restrict__ out, float* __restrict__ sums)
{
    const int oH = 2*H, oW = 2*H;
    const int ROWS = 2, NRAW = 4, NUH = ROWS+2, NUW = oW+2;
    __shared__ float rawS[3][NRAW][H];
    __shared__ float upS[3][NUH][NUW];
    __shared__ float red[256];
    __shared__ float wS[84];   // 81 weights + 3 bias

    int blk = blockIdx.x, tid = threadIdx.x;
    int n = blk / (oH/ROWS);
    int rg = blk % (oH/ROWS);
    int oh0 = rg*ROWS;

    if (tid < 81) wS[tid] = wgt[tid];
    else if (tid < 84) wS[tid] = bias[tid-81];

    int uh_lo = oh0 - 1; if (uh_lo < 0) uh_lo = 0;
    int r0 = (int)((float)uh_lo * (float)(H-1) / (float)(oH-1));

    // stage raw rows r0..r0+3 (clamped; norm+lrelu fused at load)
    for (int it = tid; it < 3*NRAW*H; it += 256){
        int ci = it / (NRAW*H);
        int rem = it - ci*(NRAW*H);
        int rr = rem / H;
        int cc = rem - rr*H;
        int gr = r0 + rr; if (gr > H-1) gr = H-1;
        float v = in_[((size_t)(n*3+ci)*H + gr)*H + cc];
        if (NORM){
            int pr = n*3+ci;
            float m_ = nsum[pr*2]*cntInv;
            float v_ = nsum[pr*2+1]*cntInv - m_*m_;
            float iv = rsqrtf(v_ + EPS);
            v = lrelu((v-m_)*iv);
        }
        rawS[ci][rr][cc] = v;
    }
    __syncthreads();

    // bilinear up-halo from LDS (zero outside plane)
    for (int it = tid; it < 3*NUH*NUW; it += 256){
        int ci = it / (NUH*NUW);
        int rem = it - ci*(NUH*NUW);
        int ur = rem / NUW;
        int uwi = rem - ur*NUW;
        int uh = oh0 - 1 + ur;
        int uw = uwi - 1;
        float val = 0.f;
        if (uh >= 0 && uh < oH && uw >= 0 && uw < oW){
            float ph = (float)uh * (float)(H-1) / (float)(oH-1);
            int i0 = (int)ph; int i1 = min(i0+1, H-1); float fh = ph - (float)i0;
            float pw = (float)uw * (float)(H-1) / (float)(oH-1);
            int j0 = (int)pw; int j1 = min(j0+1, H-1); float fw = pw - (float)j0;
            const float* q0 = rawS[ci][i0-r0];
            const float* q1 = rawS[ci][i1-r0];
            float v00=q0[j0], v01=q0[j1], v10=q1[j0], v11=q1[j1];
            float v0 = v00 + (v01-v00)*fw;
            float v1 = v10 + (v11-v10)*fw;
            val = v0 + (v1-v0)*fh;
        }
        upS[ci][ur][uwi] = val;
    }
    __syncthreads();

    // conv: P positions per thread, 3 co each
    const int P = (ROWS*oW)/256;
    float s1[3] = {0.f,0.f,0.f}, s2[3] = {0.f,0.f,0.f};
    #pragma unroll
    for (int pp = 0; pp < P; pp++){
        int pos = pp*256 + tid;
        int lrow = pos / oW, ow = pos - lrow*oW;
        int oh = oh0 + lrow;
        #pragma unroll
        for (int co=0; co<3; co++){
            float acc = wS[81+co];
            #pragma unroll
            for (int ci=0;ci<3;ci++)
                #pragma unroll
                for (int kh=0;kh<3;kh++)
                    #pragma unroll
                    for (int kw=0;kw<3;kw++)
                        acc += wS[(co*3+ci)*9 + kh*3 + kw] * upS[ci][lrow+kh][ow+kw];
            out[(((size_t)(n*3+co))*oH + oh)*oW + ow] = acc;
            s1[co] += acc; s2[co] += acc*acc;
        }
    }

    // per-co block reductions
    #pragma unroll
    for (int co=0; co<3; co++){
        red[tid] = s1[co]; __syncthreads();
        for (int o=128;o>0;o>>=1){ if(tid<o) red[tid]+=red[tid+o]; __syncthreads(); }
        float bs = red[0]; __syncthreads();
        red[tid] = s2[co]; __syncthreads();
        for (int o=128;o>0;o>>=1){ if(tid<o) red[tid]+=red[tid+o]; __syncthreads(); }
        if (tid==0){
            atomicAdd(&sums[(n*3+co)*2],   bs);
            atomicAdd(&sums[(n*3+co)*2+1], red[0]);
        }
        __syncthreads();
    }
}

__global__ void inapply_kernel(const float* __restrict__ in, const float* __restrict__ sums,
                               int planeSize, float cntInv, float* __restrict__ out)
{
    size_t idx = (size_t)blockIdx.x*256 + threadIdx.x;
    int pair = (int)(idx / planeSize);
    float m = sums[pair*2]*cntInv;
    float v = sums[pair*2+1]*cntInv - m*m;
    float inv = rsqrtf(v + EPS);
    out[idx] = lrelu((in[idx]-m)*inv);
}

// -----------------------------------------------------------------------------
// MFMA correlation, 3-term bf16 split, two-pass recompute. PASS1 applies the
// fc instance-norm inline (reads raw FC64 + SUMS+12).
template<int PASS>
__global__ __launch_bounds__(256,2) void corr_mfma(
    const short* __restrict__ PK,
    float* __restrict__ corr, float* __restrict__ SSUM,
    const float* __restrict__ FC64, const float* __restrict__ fsums,
    float* __restrict__ WARP)
{
    __shared__ short lds[32768];   // 64KB: fb_hi|fb_lo|fa_hi|fa_lo, 8192 each

    int blk = blockIdx.x;
    int qb = blk & 31, pb = (blk >> 5) & 31, n = blk >> 10;
    int tid = threadIdx.x;

    const short* pkB = PK + (((size_t)(2+n)*32 + pb) << 14);
    const short* pkA = PK + (((size_t)( n )*32 + qb) << 14);
    #pragma unroll
    for (int it=0; it<16; it++){
        int cid = it*256 + tid;
        int side = cid >> 11;
        int off  = (cid & 2047)*8;
        short8 vv = *(const short8*)((side ? pkA : pkB) + off);
        *(short8*)(lds + side*16384 + off) = vv;
    }
    __syncthreads();

    int wave = tid >> 6, lane = tid & 63;
    int wp = wave >> 1, wq = wave & 1;
    int quad = lane >> 4, l16 = lane & 15;

    f32x4 acc[4][4];
    #pragma unroll
    for (int pt=0;pt<4;pt++)
        #pragma unroll
        for (int qt=0;qt<4;qt++)
            acc[pt][qt] = (f32x4){0.f,0.f,0.f,0.f};

    #pragma unroll
    for (int kc=0;kc<2;kc++){
        int cc = kc*4 + quad;
        bf16x8 Ah[4], Al[4], Bh[4], Bl[4];
        #pragma unroll
        for (int t4=0;t4<4;t4++){
            int offA = (((wp*4+t4)*8 + cc)*16 + l16)*8;
            Ah[t4] = (bf16x8)(*(const short8*)(lds + offA));
            Al[t4] = (bf16x8)(*(const short8*)(lds + 8192 + offA));
            int offB = 16384 + (((wq*4+t4)*8 + cc)*16 + l16)*8;
            Bh[t4] = (bf16x8)(*(const short8*)(lds + offB));
            Bl[t4] = (bf16x8)(*(const short8*)(lds + 8192 + offB));
        }
        #pragma unroll
        for (int pt=0;pt<4;pt++)
            #pragma unroll
            for (int qt=0;qt<4;qt++){
                acc[pt][qt] = mfma16(Ah[pt], Bh[qt], acc[pt][qt]);
                acc[pt][qt] = mfma16(Ah[pt], Bl[qt], acc[pt][qt]);
                acc[pt][qt] = mfma16(Al[pt], Bh[qt], acc[pt][qt]);
            }
    }

    if (PASS == 0){
        float colsum[4] = {0.f,0.f,0.f,0.f};
        #pragma unroll
        for (int pt=0;pt<4;pt++)
            #pragma unroll
            for (int qt=0;qt<4;qt++)
                #pragma unroll
                for (int i=0;i<4;i++)
                    colsum[qt] += __expf(fmaf(acc[pt][qt][i], 100.f, -64.f));
        #pragma unroll
        for (int qt=0;qt<4;qt++){
            float v = colsum[qt];
            v += __shfl_xor(v, 16);
            v += __shfl_xor(v, 32);
            if (lane < 16)
                atomicAdd(&SSUM[n*4096 + qb*128 + wq*64 + qt*16 + lane], v);
        }
    } else {
        float inv4[4];
        int qoff = n*4096 + qb*128 + wq*64 + l16;
        #pragma unroll
        for (int qt=0;qt<4;qt++) inv4[qt] = 1.f / SSUM[qoff + qt*16];

        // fc instance-norm params (fused inapply)
        float fm[3], fiv[3];
        #pragma unroll
        for (int c=0;c<3;c++){
            float m_ = fsums[(n*3+c)*2]   * (1.f/4096.f);
            float v_ = fsums[(n*3+c)*2+1] * (1.f/4096.f) - m_*m_;
            fm[c] = m_; fiv[c] = rsqrtf(v_ + EPS);
        }

        float wa0[4]={0,0,0,0}, wa1[4]={0,0,0,0}, wa2[4]={0,0,0,0};
        const float* fcb = FC64 + (size_t)n*12288;
        float* corrN = corr + (size_t)n*4096*4096;
        #pragma unroll
        for (int pt=0;pt<4;pt++){
            #pragma unroll
            for (int i=0;i<4;i++){
                int p = pb*128 + wp*64 + pt*16 + quad*4 + i;
                float f0 = lrelu((fcb[p]      -fm[0])*fiv[0]);
                float f1 = lrelu((fcb[4096+p] -fm[1])*fiv[1]);
                float f2 = lrelu((fcb[8192+p] -fm[2])*fiv[2]);
                float* rowp = corrN + (size_t)p*4096 + qb*128 + wq*64 + l16;
                #pragma unroll
                for (int qt=0;qt<4;qt++){
                    float u = __expf(fmaf(acc[pt][qt][i], 100.f, -64.f)) * inv4[qt];
                    __builtin_nontemporal_store(u, &rowp[qt*16]);
                    wa0[qt] += f0*u; wa1[qt] += f1*u; wa2[qt] += f2*u;
                }
            }
        }
        #pragma unroll
        for (int qt=0;qt<4;qt++){
            float v0 = wa0[qt], v1 = wa1[qt], v2 = wa2[qt];
            v0 += __shfl_xor(v0,16); v0 += __shfl_xor(v0,32);
            v1 += __shfl_xor(v1,16); v1 += __shfl_xor(v1,32);
            v2 += __shfl_xor(v2,16); v2 += __shfl_xor(v2,32);
            if (lane < 16){
                int q = qb*128 + wq*64 + qt*16 + lane;
                atomicAdd(&WARP[(size_t)n*12288 +        q], v0);
                atomicAdd(&WARP[(size_t)n*12288 + 4096 + q], v1);
                atomicAdd(&WARP[(size_t)n*12288 + 8192 + q], v2);
            }
        }
    }
}

// -----------------------------------------------------------------------------
extern "C" void kernel_launch(void* const* d_in, const int* in_sizes, int n_in,
                              void* d_out, int out_size, void* d_ws, size_t ws_size,
                              hipStream_t stream)
{
    const float* fa_raw = (const float*)d_in[0];
    const float* fb_raw = (const float*)d_in[1];
    const float* fc_raw = (const float*)d_in[2];
    const float* Wa  = (const float*)d_in[3];
    const float* ba  = (const float*)d_in[4];
    const float* Wb  = (const float*)d_in[5];
    const float* bb  = (const float*)d_in[6];
    const float* Wc1 = (const float*)d_in[7];
    const float* bc1 = (const float*)d_in[8];
    const float* Wc2 = (const float*)d_in[9];
    const float* bc2 = (const float*)d_in[10];
    const float* Wu1 = (const float*)d_in[11];
    const float* bu1 = (const float*)d_in[12];
    const float* Wu2 = (const float*)d_in[13];
    const float* bu2 = (const float*)d_in[14];

    float* ws    = (float*)d_ws;
    float* FEAT  = ws;                  // 1048576 = [side][n][4096][64]
    float* CONV1 = FEAT  + 1048576;     // 98304
    float* FC64  = CONV1 + 98304;       // 24576
    float* CONV2 = FC64  + 24576;       // 98304
    float* CONV3 = CONV2 + 98304;       // 393216
    float* SSUM  = CONV3 + 393216;      // 8192   [zeroed]
    float* SUMS  = SSUM  + 8192;        // 48     [zeroed]
    float* FSUM  = SUMS  + 48;          // 512    [zeroed]
    float* M2SUM = FSUM  + 512;         // 256    [zeroed]
    float* WARP  = M2SUM + 256;         // 24576  [zeroed]
    float* FSTm  = WARP  + 24576;       // 256
    float* FSTi  = FSTm  + 256;         // 256
    short* PK    = (short*)(FSTi + 256); // 2097152 shorts (4 MB), 16B-aligned

    float* out_fc   = (float*)d_out;
    float* out_corr = out_fc + 393216;

    // zero atomic accumulators (SSUM..WARP contiguous, 33584 floats)
    hipMemsetAsync(SSUM, 0, (size_t)(8192 + 48 + 512 + 256 + 24576)*sizeof(float), stream);

    // stage 1: feat conv1x1 || fc conv#1   (independent work, one dispatch)
    mega1<<<640,256,0,stream>>>(fa_raw, fb_raw, Wa, Wb, ba, bb, FEAT, FSUM,
                                fc_raw, Wc1, bc1, CONV1, SUMS+0);

    // stage 2: feat IN-sum || fc conv#2 (norm-fused) || FST precompute
    mega2<<<353,256,0,stream>>>(FEAT, FSUM, M2SUM, CONV1, Wc2, bc2, SUMS, FC64,
                                FSTm, FSTi);

    // stage 3: feat recenter + L2-norm + PK pack
    feat_finish<<<64,256,0,stream>>>(FEAT, M2SUM, FSTm, FSTi, PK);

    // correlation softmax (two-pass MFMA recompute) + fused warp + fused fc-norm
    corr_mfma<0><<<2048,256,0,stream>>>(PK, out_corr, SSUM, FC64, SUMS+12, WARP);
    corr_mfma<1><<<2048,256,0,stream>>>(PK, out_corr, SSUM, FC64, SUMS+12, WARP);

    // upsample block 1: 64 -> 128 (raw WARP input), raw-row LDS staging
    upconv_lds<64,false><<<128,256,0,stream>>>(WARP, Wu1, bu1, nullptr, 0.f,
                                               CONV2, SUMS+24);
    // upsample block 2: 128 -> 256, input-norm fused, raw-row LDS staging
    upconv_lds<128,true><<<256,256,0,stream>>>(CONV2, Wu2, bu2, SUMS+24, 1.f/16384.f,
                                               CONV3, SUMS+36);
    // final instance-norm apply -> out_fc
    inapply_kernel<<<1536,256,0,stream>>>(CONV3, SUMS+36, 65536, 1.f/65536.f, out_fc);
}